// Round 1
// baseline (1769.899 us; speedup 1.0000x reference)
//
#include <hip/hip_runtime.h>
#include <math.h>

#define DM   1024
#define NH   16
#define HD   64
#define BATCH 2
#define SEQ  2048
#define MR   (BATCH*SEQ)   // 4096 rows

// ---------------------------------------------------------------------------
// C[M,1024] = A[M,1024] @ W[1024,1024]^T + bias      (fp32, 128x128 tile,
// 8x8 per thread, BK=16)
// ---------------------------------------------------------------------------
__global__ __launch_bounds__(256) void proj_gemm(
    const float* __restrict__ A, const float* __restrict__ W,
    const float* __restrict__ bias, float* __restrict__ C)
{
    __shared__ float At[16][128];
    __shared__ float Bt[16][128];
    const int tid = threadIdx.x;
    const int m0 = blockIdx.x * 128;
    const int n0 = blockIdx.y * 128;
    const int ty = tid >> 4;        // 0..15
    const int tx = tid & 15;        // 0..15
    const int lr = tid >> 1;        // 0..127
    const int lc = (tid & 1) * 8;   // 0 or 8

    float acc[8][8];
#pragma unroll
    for (int i = 0; i < 8; ++i)
#pragma unroll
        for (int j = 0; j < 8; ++j) acc[i][j] = 0.f;

    const float* Arow = A + (size_t)(m0 + lr) * DM + lc;
    const float* Wrow = W + (size_t)(n0 + lr) * DM + lc;

    for (int k0 = 0; k0 < DM; k0 += 16) {
        float4 a0 = *(const float4*)(Arow + k0);
        float4 a1 = *(const float4*)(Arow + k0 + 4);
        float4 b0 = *(const float4*)(Wrow + k0);
        float4 b1 = *(const float4*)(Wrow + k0 + 4);
        __syncthreads();   // previous compute done before overwrite
        At[lc+0][lr]=a0.x; At[lc+1][lr]=a0.y; At[lc+2][lr]=a0.z; At[lc+3][lr]=a0.w;
        At[lc+4][lr]=a1.x; At[lc+5][lr]=a1.y; At[lc+6][lr]=a1.z; At[lc+7][lr]=a1.w;
        Bt[lc+0][lr]=b0.x; Bt[lc+1][lr]=b0.y; Bt[lc+2][lr]=b0.z; Bt[lc+3][lr]=b0.w;
        Bt[lc+4][lr]=b1.x; Bt[lc+5][lr]=b1.y; Bt[lc+6][lr]=b1.z; Bt[lc+7][lr]=b1.w;
        __syncthreads();
#pragma unroll
        for (int kk = 0; kk < 16; ++kk) {
            float a[8], b[8];
            *(float4*)&a[0] = *(const float4*)&At[kk][ty*8];
            *(float4*)&a[4] = *(const float4*)&At[kk][ty*8+4];
            *(float4*)&b[0] = *(const float4*)&Bt[kk][tx*8];
            *(float4*)&b[4] = *(const float4*)&Bt[kk][tx*8+4];
#pragma unroll
            for (int i = 0; i < 8; ++i)
#pragma unroll
                for (int j = 0; j < 8; ++j)
                    acc[i][j] = fmaf(a[i], b[j], acc[i][j]);
        }
    }
#pragma unroll
    for (int i = 0; i < 8; ++i) {
        const int m = m0 + ty*8 + i;
#pragma unroll
        for (int jj = 0; jj < 2; ++jj) {
            const int n = n0 + tx*8 + jj*4;
            float4 v;
            v.x = acc[i][jj*4+0] + bias[n+0];
            v.y = acc[i][jj*4+1] + bias[n+1];
            v.z = acc[i][jj*4+2] + bias[n+2];
            v.w = acc[i][jj*4+3] + bias[n+3];
            *(float4*)&C[(size_t)m*DM + n] = v;
        }
    }
}

// ---------------------------------------------------------------------------
// center-normalize each contiguous 64-float head vector (in place)
// ---------------------------------------------------------------------------
__global__ __launch_bounds__(256) void normalize_heads(float* __restrict__ X)
{
    const int chunk = blockIdx.x * 4 + (threadIdx.x >> 6);
    const int lane  = threadIdx.x & 63;
    float x = X[(size_t)chunk*HD + lane];
    float s = x;
#pragma unroll
    for (int o = 32; o > 0; o >>= 1) s += __shfl_xor(s, o, 64);
    const float xc = x - s * (1.0f/64.0f);
    float ss = xc*xc;
#pragma unroll
    for (int o = 32; o > 0; o >>= 1) ss += __shfl_xor(ss, o, 64);
    const float inv = 1.0f / fmaxf(sqrtf(ss), 1e-12f);
    X[(size_t)chunk*HD + lane] = xc * inv;
}

// ---------------------------------------------------------------------------
// fused attention: WG = 64 q-rows for one (b,h). K/V tiles of 64 staged in
// LDS; scores -> p=exp(score-12) (|score|<=scale<12) -> row sums -> PV.
// attn written unnormalized, then rescaled in place (L2-warm).
// ---------------------------------------------------------------------------
__global__ __launch_bounds__(256) void attn_kernel(
    const float* __restrict__ Q, const float* __restrict__ K,
    const float* __restrict__ V, const int* __restrict__ mask,
    const float* __restrict__ scale_p,
    float* __restrict__ attn, float* __restrict__ ctx)
{
    __shared__ float Qt[HD][64];   // [d][q]
    __shared__ float Kt[HD][64];   // [d][k]
    __shared__ float Vs[64][HD];   // [k][d]
    __shared__ float Pt[64][64];   // [k][q]
    __shared__ int   mk[64];

    const int b  = blockIdx.z;
    const int h  = blockIdx.y;
    const int q0 = blockIdx.x * 64;
    const int tid = threadIdx.x;
    const int ty = tid >> 4, tx = tid & 15;
    const float s2 = scale_p[0] * 1.44269504f;   // scale*log2(e)
    const float c2 = -12.0f * 1.44269504f;       // -12*log2(e)

    // stage Q tile transposed
    {
        const int r  = tid >> 2;          // 0..63
        const int c0 = (tid & 3) * 16;    // 0,16,32,48
        const float* src = Q + ((size_t)(b*SEQ + q0 + r))*DM + h*HD + c0;
#pragma unroll
        for (int i = 0; i < 4; ++i) {
            float4 v = *(const float4*)(src + i*4);
            Qt[c0+i*4+0][r] = v.x;
            Qt[c0+i*4+1][r] = v.y;
            Qt[c0+i*4+2][r] = v.z;
            Qt[c0+i*4+3][r] = v.w;
        }
    }

    float cacc[4][4];
#pragma unroll
    for (int i = 0; i < 4; ++i)
#pragma unroll
        for (int j = 0; j < 4; ++j) cacc[i][j] = 0.f;
    float rs[4] = {0.f, 0.f, 0.f, 0.f};

    float* attn_base = attn + ((size_t)(b*NH + h)*SEQ + q0) * SEQ;

    for (int kt = 0; kt < SEQ/64; ++kt) {
        const int kk = kt * 64;
        __syncthreads();   // previous PV finished before restaging
        {
            const int r  = tid >> 2;
            const int c0 = (tid & 3) * 16;
            const float* ksrc = K + ((size_t)(b*SEQ + kk + r))*DM + h*HD + c0;
            const float* vsrc = V + ((size_t)(b*SEQ + kk + r))*DM + h*HD + c0;
#pragma unroll
            for (int i = 0; i < 4; ++i) {
                float4 kv = *(const float4*)(ksrc + i*4);
                Kt[c0+i*4+0][r] = kv.x;
                Kt[c0+i*4+1][r] = kv.y;
                Kt[c0+i*4+2][r] = kv.z;
                Kt[c0+i*4+3][r] = kv.w;
                float4 vv = *(const float4*)(vsrc + i*4);
                *(float4*)&Vs[r][c0+i*4] = vv;
            }
            if (tid < 64) mk[tid] = mask[b*SEQ + kk + tid];
        }
        __syncthreads();

        // scores: 4x4 per thread over (q,k)
        float sacc[4][4];
#pragma unroll
        for (int i = 0; i < 4; ++i)
#pragma unroll
            for (int j = 0; j < 4; ++j) sacc[i][j] = 0.f;
#pragma unroll 8
        for (int d = 0; d < HD; ++d) {
            float qf[4], kf[4];
            *(float4*)qf = *(const float4*)&Qt[d][ty*4];
            *(float4*)kf = *(const float4*)&Kt[d][tx*4];
#pragma unroll
            for (int i = 0; i < 4; ++i)
#pragma unroll
                for (int j = 0; j < 4; ++j)
                    sacc[i][j] = fmaf(qf[i], kf[j], sacc[i][j]);
        }

        // p = exp(score - 12), masked -> exact 0
        float p[4][4];
#pragma unroll
        for (int j = 0; j < 4; ++j) {
            const bool dead = (mk[tx*4+j] == 0);
#pragma unroll
            for (int i = 0; i < 4; ++i) {
                float e = exp2f(fmaf(sacc[i][j], s2, c2));
                p[i][j] = dead ? 0.f : e;
            }
        }

        // row sums across the 16 tx threads (contiguous lanes)
#pragma unroll
        for (int i = 0; i < 4; ++i) {
            float t = p[i][0] + p[i][1] + p[i][2] + p[i][3];
            t += __shfl_xor(t, 1, 16);
            t += __shfl_xor(t, 2, 16);
            t += __shfl_xor(t, 4, 16);
            t += __shfl_xor(t, 8, 16);
            rs[i] += t;
        }

        // store unnormalized attn (rescaled later)
#pragma unroll
        for (int i = 0; i < 4; ++i) {
            float4 v; v.x = p[i][0]; v.y = p[i][1]; v.z = p[i][2]; v.w = p[i][3];
            *(float4*)&attn_base[(size_t)(ty*4+i)*SEQ + kk + tx*4] = v;
        }

        // Pt[k][q] for the PV GEMM
#pragma unroll
        for (int j = 0; j < 4; ++j) {
            float4 v; v.x = p[0][j]; v.y = p[1][j]; v.z = p[2][j]; v.w = p[3][j];
            *(float4*)&Pt[tx*4+j][ty*4] = v;
        }
        __syncthreads();

        // PV: ctx[q][d] += sum_k p[q][k]*V[k][d]; thread tile 4q x 4d
#pragma unroll 8
        for (int k = 0; k < 64; ++k) {
            float pf[4], vf[4];
            *(float4*)pf = *(const float4*)&Pt[k][ty*4];
            *(float4*)vf = *(const float4*)&Vs[k][tx*4];
#pragma unroll
            for (int i = 0; i < 4; ++i)
#pragma unroll
                for (int j = 0; j < 4; ++j)
                    cacc[i][j] = fmaf(pf[i], vf[j], cacc[i][j]);
        }
    }

    float rinv[4];
#pragma unroll
    for (int i = 0; i < 4; ++i) rinv[i] = 1.0f / fmaxf(rs[i], 1e-30f);

    // write ctx (pre-out-projection), [B,S,D] layout
#pragma unroll
    for (int i = 0; i < 4; ++i) {
        float4 v;
        v.x = cacc[i][0]*rinv[i]; v.y = cacc[i][1]*rinv[i];
        v.z = cacc[i][2]*rinv[i]; v.w = cacc[i][3]*rinv[i];
        *(float4*)&ctx[((size_t)(b*SEQ + q0 + ty*4 + i))*DM + h*HD + tx*4] = v;
    }

    // rescale attn rows in place (each element touched by exactly one thread)
    for (int kt = 0; kt < SEQ/64; ++kt) {
#pragma unroll
        for (int i = 0; i < 4; ++i) {
            float4* ptr = (float4*)&attn_base[(size_t)(ty*4+i)*SEQ + kt*64 + tx*4];
            float4 v = *ptr;
            v.x *= rinv[i]; v.y *= rinv[i]; v.z *= rinv[i]; v.w *= rinv[i];
            *ptr = v;
        }
    }
}

// ---------------------------------------------------------------------------
extern "C" void kernel_launch(void* const* d_in, const int* in_sizes, int n_in,
                              void* d_out, int out_size, void* d_ws, size_t ws_size,
                              hipStream_t stream)
{
    const float* query = (const float*)d_in[0];
    const float* key   = (const float*)d_in[1];
    const float* value = (const float*)d_in[2];
    const int*   mask  = (const int*)d_in[3];
    const float* Wq = (const float*)d_in[4];
    const float* bq = (const float*)d_in[5];
    const float* Wk = (const float*)d_in[6];
    const float* bk = (const float*)d_in[7];
    const float* Wv = (const float*)d_in[8];
    const float* bv = (const float*)d_in[9];
    const float* Wo = (const float*)d_in[10];
    const float* bo = (const float*)d_in[11];
    const float* scale = (const float*)d_in[12];

    float* out_ctx  = (float*)d_out;                     // [B,S,D]
    float* out_attn = (float*)d_out + (size_t)MR*DM;     // [B,H,S,S]

    const size_t tsz = (size_t)MR * DM;                  // 4.19M floats
    float* Qb = (float*)d_ws;
    float* Kb = Qb + tsz;
    float* Vb = Kb + tsz;
    // ctx scratch: its own buffer if ws allows, else safely alias Qb
    // (each (b,h,q)-block of Q is consumed into LDS by the only WG that
    //  later writes that exact ctx block)
    float* Cb = (ws_size >= 4*tsz*sizeof(float)) ? (Vb + tsz) : Qb;

    dim3 gg(MR/128, DM/128);
    proj_gemm<<<gg, 256, 0, stream>>>(query, Wq, bq, Qb);
    proj_gemm<<<gg, 256, 0, stream>>>(key,   Wk, bk, Kb);
    proj_gemm<<<gg, 256, 0, stream>>>(value, Wv, bv, Vb);
    normalize_heads<<<(MR*NH)/4, 256, 0, stream>>>(Qb);
    normalize_heads<<<(MR*NH)/4, 256, 0, stream>>>(Kb);
    attn_kernel<<<dim3(SEQ/64, NH, BATCH), 256, 0, stream>>>(
        Qb, Kb, Vb, mask, scale, out_attn, Cb);
    proj_gemm<<<gg, 256, 0, stream>>>(Cb, Wo, bo, out_ctx);
}

// Round 2
// 945.178 us; speedup vs baseline: 1.8726x; 1.8726x over previous
//
#include <hip/hip_runtime.h>
#include <math.h>

#define DM   1024
#define NH   16
#define HD   64
#define BATCH 2
#define SEQ  2048
#define MR   (BATCH*SEQ)   // 4096 rows

typedef __attribute__((ext_vector_type(8))) short bf16x8;
typedef __attribute__((ext_vector_type(4))) float f32x4;

__device__ __forceinline__ unsigned short f2bf(float x) {
    unsigned u = __builtin_bit_cast(unsigned, x);
    u = (u + 0x7FFFu + ((u >> 16) & 1u)) >> 16;
    return (unsigned short)u;
}
__device__ __forceinline__ float bf2f(unsigned short s) {
    unsigned u = ((unsigned)s) << 16;
    return __builtin_bit_cast(float, u);
}
__device__ __forceinline__ uint4 packhi8(const float* f, unsigned short* h) {
#pragma unroll
    for (int k = 0; k < 8; ++k) h[k] = f2bf(f[k]);
    uint4 u;
    u.x = (unsigned)h[0] | ((unsigned)h[1] << 16);
    u.y = (unsigned)h[2] | ((unsigned)h[3] << 16);
    u.z = (unsigned)h[4] | ((unsigned)h[5] << 16);
    u.w = (unsigned)h[6] | ((unsigned)h[7] << 16);
    return u;
}

// ---------------------------------------------------------------------------
// fp32 -> bf16 split (hi + lo) / single conversions for weights
// ---------------------------------------------------------------------------
__global__ __launch_bounds__(256) void convert_split(
    const float* __restrict__ src, unsigned short* __restrict__ hi,
    unsigned short* __restrict__ lo, int n4)
{
    int i = blockIdx.x * 256 + threadIdx.x;
    if (i >= n4) return;
    float4 v = ((const float4*)src)[i];
    float f[4] = {v.x, v.y, v.z, v.w};
    unsigned short h[4], l[4];
#pragma unroll
    for (int k = 0; k < 4; ++k) {
        h[k] = f2bf(f[k]);
        l[k] = f2bf(f[k] - bf2f(h[k]));
    }
    ((ushort4*)hi)[i] = make_ushort4(h[0], h[1], h[2], h[3]);
    ((ushort4*)lo)[i] = make_ushort4(l[0], l[1], l[2], l[3]);
}

__global__ __launch_bounds__(256) void convert_single(
    const float* __restrict__ src, unsigned short* __restrict__ dst, int n4)
{
    int i = blockIdx.x * 256 + threadIdx.x;
    if (i >= n4) return;
    float4 v = ((const float4*)src)[i];
    ((ushort4*)dst)[i] = make_ushort4(f2bf(v.x), f2bf(v.y), f2bf(v.z), f2bf(v.w));
}

// ---------------------------------------------------------------------------
// MFMA projection GEMM: C[M,1024] = A[M,1024] @ W[1024,1024]^T + bias
// Tile 64m x 128n, BK=32, 256 threads (4 waves, 2x2 of 32m x 64n each).
// MODE 0: A fp32 (split to hi/lo in staging), W pre-split hi/lo (3-term MFMA,
//         ~fp32 accuracy). Epilogue: +bias, center-normalize per 64-col head,
//         output split bf16 (hi,lo).
// MODE 1: A fp32 -> bf16, W bf16. Epilogue: +bias, bf16 output TRANSPOSED
//         per head: out[((b*NH+h)*HD+d)*SEQ + s].
// MODE 2: A bf16, W bf16. Epilogue: +bias, fp32 output row-major.
// ---------------------------------------------------------------------------
template<int MODE>
__global__ __launch_bounds__(256) void proj_gemm(
    const void* __restrict__ Aptr,
    const unsigned short* __restrict__ Bhi, const unsigned short* __restrict__ Blo,
    const float* __restrict__ bias,
    void* __restrict__ out0, unsigned short* __restrict__ out1)
{
    __shared__ __align__(16) short As[2][64][40];    // 32 k + 8 pad
    __shared__ __align__(16) short Bs[2][128][40];

    const int tid  = threadIdx.x;
    const int wave = tid >> 6, lane = tid & 63;
    const int quad = lane >> 4, lr = lane & 15;
    const int wy = wave >> 1, wx = wave & 1;
    const int m0 = blockIdx.x * 64, n0 = blockIdx.y * 128;

    f32x4 acc[2][4];
#pragma unroll
    for (int i = 0; i < 2; ++i)
#pragma unroll
        for (int j = 0; j < 4; ++j) acc[i][j] = (f32x4){0.f, 0.f, 0.f, 0.f};

    const int arow = tid >> 2, aseg = tid & 3;   // A: 64 rows x 4 segs of 8
    const int brow = tid >> 1, bseg = tid & 1;   // B: 128 rows x 2 segs of 16

    for (int k0 = 0; k0 < DM; k0 += 32) {
        __syncthreads();
        // ---- stage A ----
        if (MODE == 2) {
            const unsigned short* A = (const unsigned short*)Aptr;
            *(uint4*)&As[0][arow][aseg * 8] =
                *(const uint4*)&A[(size_t)(m0 + arow) * DM + k0 + aseg * 8];
        } else {
            const float* A = (const float*)Aptr;
            const float* ap = &A[(size_t)(m0 + arow) * DM + k0 + aseg * 8];
            float4 v0 = *(const float4*)ap;
            float4 v1 = *(const float4*)(ap + 4);
            float f[8] = {v0.x, v0.y, v0.z, v0.w, v1.x, v1.y, v1.z, v1.w};
            unsigned short h[8];
            uint4 hv = packhi8(f, h);
            *(uint4*)&As[0][arow][aseg * 8] = hv;
            if (MODE == 0) {
                float fl[8];
#pragma unroll
                for (int k = 0; k < 8; ++k) fl[k] = f[k] - bf2f(h[k]);
                unsigned short hl[8];
                uint4 lv = packhi8(fl, hl);
                *(uint4*)&As[1][arow][aseg * 8] = lv;
            }
        }
        // ---- stage B ----
        {
            const size_t bo = (size_t)(n0 + brow) * DM + k0 + bseg * 16;
            *(uint4*)&Bs[0][brow][bseg * 16]     = *(const uint4*)&Bhi[bo];
            *(uint4*)&Bs[0][brow][bseg * 16 + 8] = *(const uint4*)&Bhi[bo + 8];
            if (MODE == 0) {
                *(uint4*)&Bs[1][brow][bseg * 16]     = *(const uint4*)&Blo[bo];
                *(uint4*)&Bs[1][brow][bseg * 16 + 8] = *(const uint4*)&Blo[bo + 8];
            }
        }
        __syncthreads();
        // ---- fragments + MFMA ----
        bf16x8 ah[2], al[2], bh[4], bl[4];
#pragma unroll
        for (int i = 0; i < 2; ++i) {
            ah[i] = *(const bf16x8*)&As[0][wy * 32 + i * 16 + lr][quad * 8];
            if (MODE == 0) al[i] = *(const bf16x8*)&As[1][wy * 32 + i * 16 + lr][quad * 8];
        }
#pragma unroll
        for (int j = 0; j < 4; ++j) {
            bh[j] = *(const bf16x8*)&Bs[0][wx * 64 + j * 16 + lr][quad * 8];
            if (MODE == 0) bl[j] = *(const bf16x8*)&Bs[1][wx * 64 + j * 16 + lr][quad * 8];
        }
#pragma unroll
        for (int i = 0; i < 2; ++i)
#pragma unroll
            for (int j = 0; j < 4; ++j) {
                acc[i][j] = __builtin_amdgcn_mfma_f32_16x16x32_bf16(ah[i], bh[j], acc[i][j], 0, 0, 0);
                if (MODE == 0) {
                    acc[i][j] = __builtin_amdgcn_mfma_f32_16x16x32_bf16(ah[i], bl[j], acc[i][j], 0, 0, 0);
                    acc[i][j] = __builtin_amdgcn_mfma_f32_16x16x32_bf16(al[i], bh[j], acc[i][j], 0, 0, 0);
                }
            }
    }

    // ---- epilogue ----
    float bj[4];
#pragma unroll
    for (int j = 0; j < 4; ++j) bj[j] = bias[n0 + wx * 64 + j * 16 + lr];

    if (MODE == 0) {
        unsigned short* Ohi = (unsigned short*)out0;
#pragma unroll
        for (int i = 0; i < 2; ++i) {
#pragma unroll
            for (int r = 0; r < 4; ++r) {
                float x[4];
#pragma unroll
                for (int j = 0; j < 4; ++j) x[j] = acc[i][j][r] + bj[j];
                float t = x[0] + x[1] + x[2] + x[3];
                t += __shfl_xor(t, 1, 16);
                t += __shfl_xor(t, 2, 16);
                t += __shfl_xor(t, 4, 16);
                t += __shfl_xor(t, 8, 16);
                const float mean = t * (1.0f / 64.0f);
                float ss = 0.f;
#pragma unroll
                for (int j = 0; j < 4; ++j) { x[j] -= mean; ss += x[j] * x[j]; }
                ss += __shfl_xor(ss, 1, 16);
                ss += __shfl_xor(ss, 2, 16);
                ss += __shfl_xor(ss, 4, 16);
                ss += __shfl_xor(ss, 8, 16);
                const float inv = 1.0f / fmaxf(sqrtf(ss), 1e-12f);
                const int row = m0 + wy * 32 + i * 16 + quad * 4 + r;
#pragma unroll
                for (int j = 0; j < 4; ++j) {
                    const float y = x[j] * inv;
                    const unsigned short hh = f2bf(y);
                    const unsigned short ll = f2bf(y - bf2f(hh));
                    const size_t o = (size_t)row * DM + n0 + wx * 64 + j * 16 + lr;
                    Ohi[o]  = hh;
                    out1[o] = ll;
                }
            }
        }
    } else if (MODE == 1) {
        unsigned short* Vg = (unsigned short*)out0;
        const int h = (n0 + wx * 64) >> 6;
#pragma unroll
        for (int i = 0; i < 2; ++i) {
            const int grow = m0 + wy * 32 + i * 16 + quad * 4;
            const int bb = grow >> 11, ss = grow & (SEQ - 1);
#pragma unroll
            for (int j = 0; j < 4; ++j) {
                const int d = j * 16 + lr;
                ushort4 pk;
                pk.x = f2bf(acc[i][j][0] + bj[j]);
                pk.y = f2bf(acc[i][j][1] + bj[j]);
                pk.z = f2bf(acc[i][j][2] + bj[j]);
                pk.w = f2bf(acc[i][j][3] + bj[j]);
                *(ushort4*)&Vg[((size_t)(bb * NH + h) * HD + d) * SEQ + ss] = pk;
            }
        }
    } else {
        float* O = (float*)out0;
#pragma unroll
        for (int i = 0; i < 2; ++i)
#pragma unroll
            for (int j = 0; j < 4; ++j)
#pragma unroll
                for (int r = 0; r < 4; ++r)
                    O[(size_t)(m0 + wy * 32 + i * 16 + quad * 4 + r) * DM +
                      n0 + wx * 64 + j * 16 + lr] = acc[i][j][r] + bj[j];
    }
}

// ---------------------------------------------------------------------------
// Fused attention, two-phase, MFMA.
// WG = 64 q-rows of one (b,h); 4 waves, wave w owns q-strip [16w,16w+16).
// Phase 1: S = scale*Q·K^T via split-bf16 MFMA (3 terms), row-sums of
//          exp2(S*log2e - 12*log2e) with mask. No stores.
// Phase 2: recompute S, p_norm = p * rinv, write attn (only once!), bf16
//          P -> LDS (same-wave rows only -> no barrier), PV via MFMA.
// Q fragments held in registers for the whole kernel.
// ---------------------------------------------------------------------------
__global__ __launch_bounds__(256) void attn_fused(
    const unsigned short* __restrict__ Qhi, const unsigned short* __restrict__ Qlo,
    const unsigned short* __restrict__ Khi, const unsigned short* __restrict__ Klo,
    const unsigned short* __restrict__ Vg,  const int* __restrict__ mask,
    const float* __restrict__ scale_p,
    float* __restrict__ attn, unsigned short* __restrict__ ctxb)
{
    __shared__ __align__(16) short KHs[64][72];
    __shared__ __align__(16) short KLs[64][72];
    __shared__ __align__(16) short Vs[64][72];
    __shared__ __align__(16) short Ps[64][72];
    __shared__ int mk[64];

    const int tid = threadIdx.x;
    const int w = tid >> 6, lane = tid & 63;
    const int quad = lane >> 4, lr = lane & 15;
    const int b = blockIdx.z, h = blockIdx.y, q0 = blockIdx.x * 64;

    const float scl = scale_p[0];
    const float s2 = scl * 1.44269504089f;
    const float c2 = -12.0f * 1.44269504089f;

    const int r0 = tid >> 3,        c0 = (tid & 7) * 8;   // granule 0
    const int r1 = (tid >> 3) + 32, c1 = (tid & 7) * 8;   // granule 1

    // ---- stage Q (using KHs/KLs as temp), grab register fragments ----
    {
        const size_t base = ((size_t)(b * SEQ + q0)) * DM + h * HD;
        *(uint4*)&KHs[r0][c0] = *(const uint4*)&Qhi[base + (size_t)r0 * DM + c0];
        *(uint4*)&KHs[r1][c1] = *(const uint4*)&Qhi[base + (size_t)r1 * DM + c1];
        *(uint4*)&KLs[r0][c0] = *(const uint4*)&Qlo[base + (size_t)r0 * DM + c0];
        *(uint4*)&KLs[r1][c1] = *(const uint4*)&Qlo[base + (size_t)r1 * DM + c1];
    }
    __syncthreads();
    bf16x8 qh[2], ql[2];
#pragma unroll
    for (int kc = 0; kc < 2; ++kc) {
        qh[kc] = *(const bf16x8*)&KHs[w * 16 + lr][kc * 32 + quad * 8];
        ql[kc] = *(const bf16x8*)&KLs[w * 16 + lr][kc * 32 + quad * 8];
    }

    float rs[4] = {0.f, 0.f, 0.f, 0.f};

    // ---- phase 1: denominators ----
    for (int kt = 0; kt < SEQ / 64; ++kt) {
        const int kk = kt * 64;
        const size_t kb = ((size_t)(b * SEQ + kk)) * DM + h * HD;
        __syncthreads();
        *(uint4*)&KHs[r0][c0] = *(const uint4*)&Khi[kb + (size_t)r0 * DM + c0];
        *(uint4*)&KHs[r1][c1] = *(const uint4*)&Khi[kb + (size_t)r1 * DM + c1];
        *(uint4*)&KLs[r0][c0] = *(const uint4*)&Klo[kb + (size_t)r0 * DM + c0];
        *(uint4*)&KLs[r1][c1] = *(const uint4*)&Klo[kb + (size_t)r1 * DM + c1];
        if (tid < 64) mk[tid] = mask[b * SEQ + kk + tid];
        __syncthreads();
#pragma unroll
        for (int j = 0; j < 4; ++j) {
            bf16x8 bh0 = *(const bf16x8*)&KHs[j * 16 + lr][quad * 8];
            bf16x8 bh1 = *(const bf16x8*)&KHs[j * 16 + lr][32 + quad * 8];
            bf16x8 bl0 = *(const bf16x8*)&KLs[j * 16 + lr][quad * 8];
            bf16x8 bl1 = *(const bf16x8*)&KLs[j * 16 + lr][32 + quad * 8];
            f32x4 sa = (f32x4){0.f, 0.f, 0.f, 0.f};
            sa = __builtin_amdgcn_mfma_f32_16x16x32_bf16(qh[0], bh0, sa, 0, 0, 0);
            sa = __builtin_amdgcn_mfma_f32_16x16x32_bf16(ql[0], bh0, sa, 0, 0, 0);
            sa = __builtin_amdgcn_mfma_f32_16x16x32_bf16(qh[0], bl0, sa, 0, 0, 0);
            sa = __builtin_amdgcn_mfma_f32_16x16x32_bf16(qh[1], bh1, sa, 0, 0, 0);
            sa = __builtin_amdgcn_mfma_f32_16x16x32_bf16(ql[1], bh1, sa, 0, 0, 0);
            sa = __builtin_amdgcn_mfma_f32_16x16x32_bf16(qh[1], bl1, sa, 0, 0, 0);
            const float mcol = mk[j * 16 + lr] ? 1.0f : 0.0f;
#pragma unroll
            for (int r = 0; r < 4; ++r)
                rs[r] += mcol * exp2f(fmaf(sa[r], s2, c2));
        }
    }

    float rinv[4];
#pragma unroll
    for (int r = 0; r < 4; ++r) {
        float t = rs[r];
        t += __shfl_xor(t, 1, 16);
        t += __shfl_xor(t, 2, 16);
        t += __shfl_xor(t, 4, 16);
        t += __shfl_xor(t, 8, 16);
        rinv[r] = 1.0f / fmaxf(t, 1e-30f);
    }

    f32x4 acc_o[4];
#pragma unroll
    for (int dt = 0; dt < 4; ++dt) acc_o[dt] = (f32x4){0.f, 0.f, 0.f, 0.f};

    // ---- phase 2: attn store + PV ----
    for (int kt = 0; kt < SEQ / 64; ++kt) {
        const int kk = kt * 64;
        const size_t kb = ((size_t)(b * SEQ + kk)) * DM + h * HD;
        const size_t vb = ((size_t)((b * NH + h) * HD)) * SEQ + kk;
        __syncthreads();
        *(uint4*)&KHs[r0][c0] = *(const uint4*)&Khi[kb + (size_t)r0 * DM + c0];
        *(uint4*)&KHs[r1][c1] = *(const uint4*)&Khi[kb + (size_t)r1 * DM + c1];
        *(uint4*)&KLs[r0][c0] = *(const uint4*)&Klo[kb + (size_t)r0 * DM + c0];
        *(uint4*)&KLs[r1][c1] = *(const uint4*)&Klo[kb + (size_t)r1 * DM + c1];
        *(uint4*)&Vs[r0][c0]  = *(const uint4*)&Vg[vb + (size_t)r0 * SEQ + c0];
        *(uint4*)&Vs[r1][c1]  = *(const uint4*)&Vg[vb + (size_t)r1 * SEQ + c1];
        if (tid < 64) mk[tid] = mask[b * SEQ + kk + tid];
        __syncthreads();
#pragma unroll
        for (int j = 0; j < 4; ++j) {
            bf16x8 bh0 = *(const bf16x8*)&KHs[j * 16 + lr][quad * 8];
            bf16x8 bh1 = *(const bf16x8*)&KHs[j * 16 + lr][32 + quad * 8];
            bf16x8 bl0 = *(const bf16x8*)&KLs[j * 16 + lr][quad * 8];
            bf16x8 bl1 = *(const bf16x8*)&KLs[j * 16 + lr][32 + quad * 8];
            f32x4 sa = (f32x4){0.f, 0.f, 0.f, 0.f};
            sa = __builtin_amdgcn_mfma_f32_16x16x32_bf16(qh[0], bh0, sa, 0, 0, 0);
            sa = __builtin_amdgcn_mfma_f32_16x16x32_bf16(ql[0], bh0, sa, 0, 0, 0);
            sa = __builtin_amdgcn_mfma_f32_16x16x32_bf16(qh[0], bl0, sa, 0, 0, 0);
            sa = __builtin_amdgcn_mfma_f32_16x16x32_bf16(qh[1], bh1, sa, 0, 0, 0);
            sa = __builtin_amdgcn_mfma_f32_16x16x32_bf16(ql[1], bh1, sa, 0, 0, 0);
            sa = __builtin_amdgcn_mfma_f32_16x16x32_bf16(qh[1], bl1, sa, 0, 0, 0);
            const float mcol = mk[j * 16 + lr] ? 1.0f : 0.0f;
#pragma unroll
            for (int r = 0; r < 4; ++r) {
                const float pn = mcol * exp2f(fmaf(sa[r], s2, c2)) * rinv[r];
                const int qrow = q0 + w * 16 + quad * 4 + r;
                attn[((size_t)(b * NH + h) * SEQ + qrow) * SEQ + kk + j * 16 + lr] = pn;
                Ps[w * 16 + quad * 4 + r][j * 16 + lr] = (short)f2bf(pn);
            }
        }
        // PV: wave reads only its own Ps rows (written above) -> no barrier
        bf16x8 pa0 = *(const bf16x8*)&Ps[w * 16 + lr][quad * 8];
        bf16x8 pa1 = *(const bf16x8*)&Ps[w * 16 + lr][32 + quad * 8];
#pragma unroll
        for (int dt = 0; dt < 4; ++dt) {
            bf16x8 bv0 = *(const bf16x8*)&Vs[dt * 16 + lr][quad * 8];
            bf16x8 bv1 = *(const bf16x8*)&Vs[dt * 16 + lr][32 + quad * 8];
            acc_o[dt] = __builtin_amdgcn_mfma_f32_16x16x32_bf16(pa0, bv0, acc_o[dt], 0, 0, 0);
            acc_o[dt] = __builtin_amdgcn_mfma_f32_16x16x32_bf16(pa1, bv1, acc_o[dt], 0, 0, 0);
        }
    }

    // ---- ctx out (bf16, row-major [B,S,D]) ----
#pragma unroll
    for (int dt = 0; dt < 4; ++dt)
#pragma unroll
        for (int r = 0; r < 4; ++r)
            ctxb[((size_t)(b * SEQ + q0 + w * 16 + quad * 4 + r)) * DM +
                 h * HD + dt * 16 + lr] = (unsigned short)f2bf(acc_o[dt][r]);
}

// ---------------------------------------------------------------------------
extern "C" void kernel_launch(void* const* d_in, const int* in_sizes, int n_in,
                              void* d_out, int out_size, void* d_ws, size_t ws_size,
                              hipStream_t stream)
{
    const float* query = (const float*)d_in[0];
    const float* key   = (const float*)d_in[1];
    const float* value = (const float*)d_in[2];
    const int*   mask  = (const int*)d_in[3];
    const float* Wq = (const float*)d_in[4];
    const float* bq = (const float*)d_in[5];
    const float* Wk = (const float*)d_in[6];
    const float* bk = (const float*)d_in[7];
    const float* Wv = (const float*)d_in[8];
    const float* bv = (const float*)d_in[9];
    const float* Wo = (const float*)d_in[10];
    const float* bo = (const float*)d_in[11];
    const float* scale = (const float*)d_in[12];

    float* out_ctx  = (float*)d_out;                 // [B,S,DM]
    float* out_attn = out_ctx + (size_t)MR * DM;     // [B,NH,S,S]

    const size_t WSZ = (size_t)DM * DM;   // 1M elems
    const size_t TSZ = (size_t)MR * DM;   // 4M elems
    unsigned short* p = (unsigned short*)d_ws;
    unsigned short* Wq_hi = p; p += WSZ;
    unsigned short* Wq_lo = p; p += WSZ;
    unsigned short* Wk_hi = p; p += WSZ;
    unsigned short* Wk_lo = p; p += WSZ;
    unsigned short* Wv_b  = p; p += WSZ;
    unsigned short* Wo_b  = p; p += WSZ;
    unsigned short* Qn_hi = p; p += TSZ;
    unsigned short* Qn_lo = p; p += TSZ;
    unsigned short* Kn_hi = p; p += TSZ;
    unsigned short* Kn_lo = p; p += TSZ;
    unsigned short* Vg    = p; p += TSZ;
    // ctxb aliases Wq_hi..Wk_lo (4*WSZ == TSZ elems), dead after Q/K proj
    unsigned short* ctxb  = Wq_hi;

    convert_split <<<1024, 256, 0, stream>>>(Wq, Wq_hi, Wq_lo, 262144);
    convert_split <<<1024, 256, 0, stream>>>(Wk, Wk_hi, Wk_lo, 262144);
    convert_single<<<1024, 256, 0, stream>>>(Wv, Wv_b, 262144);
    convert_single<<<1024, 256, 0, stream>>>(Wo, Wo_b, 262144);

    dim3 gg(MR / 64, DM / 128);
    proj_gemm<0><<<gg, 256, 0, stream>>>(query, Wq_hi, Wq_lo, bq, Qn_hi, Qn_lo);
    proj_gemm<0><<<gg, 256, 0, stream>>>(key,   Wk_hi, Wk_lo, bk, Kn_hi, Kn_lo);
    proj_gemm<1><<<gg, 256, 0, stream>>>(value, Wv_b, nullptr, bv, Vg, nullptr);

    attn_fused<<<dim3(SEQ / 64, NH, BATCH), 256, 0, stream>>>(
        Qn_hi, Qn_lo, Kn_hi, Kn_lo, Vg, mask, scale, out_attn, ctxb);

    proj_gemm<2><<<gg, 256, 0, stream>>>(ctxb, Wo_b, nullptr, bo, out_ctx, nullptr);
}